// Round 6
// baseline (275.085 us; speedup 1.0000x reference)
//
#include <hip/hip_runtime.h>
#include <math.h>

typedef __bf16 bf16;
typedef __bf16 bf16x4 __attribute__((ext_vector_type(4)));
typedef __bf16 bf16x8 __attribute__((ext_vector_type(8)));
typedef unsigned short u16;
typedef unsigned short u16x4 __attribute__((ext_vector_type(4)));
typedef unsigned short u16x8 __attribute__((ext_vector_type(8)));
typedef float f32x4 __attribute__((ext_vector_type(4)));
typedef float f32x16 __attribute__((ext_vector_type(16)));
typedef unsigned int u32x4 __attribute__((ext_vector_type(4)));

// ---------------------------------------------------------------------------
// prep_all: merged weight-prep (one launch instead of two).
// blocks [0,392): Wl1 f32 [12544][128] -> bf16 [128][12544], K permuted
//   k' = site*64+cout <-> Wl1 row k = cout*196+site.  s=b>>1, cg=b&1.
// blocks [392,466): W2 -> conv2 B-frag buffer w2r; W1 -> conv1 B-frag w1f.
// ---------------------------------------------------------------------------
__global__ void prep_all(const float* __restrict__ W2, bf16* __restrict__ w2r,
                         const float* __restrict__ W1, bf16* __restrict__ w1f,
                         const float* __restrict__ Wl1, bf16* __restrict__ wl1t) {
    __shared__ float tile[32 * 129];
    const int b = blockIdx.x;
    const int t = threadIdx.x;
    if (b < 392) {
        const int s  = b >> 1;
        const int cg = b & 1;
        for (int e = t; e < 4096; e += 256) {
            int cl = e >> 7, n = e & 127;
            tile[cl * 129 + n] = Wl1[((long)(cg * 32 + cl) * 196 + s) * 128 + n];
        }
        __syncthreads();
        for (int e = t; e < 4096; e += 256) {
            int n = e >> 5, cl = e & 31;
            wl1t[(long)n * 12544 + s * 64 + cg * 32 + cl] = (bf16)tile[cl * 129 + n];
        }
    } else {
        int e = (b - 392) * 256 + t;
        if (e < 18432) {
            int j  = e & 7;
            int l  = (e >> 3) & 63;
            int f  = e >> 9;
            int s  = f >> 1;
            int nt = f & 1;
            int tap  = s >> 1;
            int ci   = (s & 1) * 16 + (l >> 5) * 8 + j;
            int cout = nt * 32 + (l & 31);
            w2r[e] = (bf16)W2[cout * 288 + ci * 9 + tap];
        } else {
            int e2 = e - 18432;
            if (e2 < 512) {
                int j = e2 & 7;
                int l = e2 >> 3;
                int k = (l >> 5) * 8 + j;       // tap index (K)
                int n = l & 31;                 // cout
                w1f[e2] = (k < 9) ? (bf16)W1[n * 9 + k] : (bf16)0.f;
            }
        }
    }
}

// ---------------------------------------------------------------------------
// conv_fused R19: R18 ((256,4)) + REGISTER SHAVE.  R18 spilled by only
// ~3-5 regs (WRITE_SIZE +20 MB scratch).  Two fixes:
//  (1) breg[18] (72 regs) load MOVED to after conv1 loop — it was live
//      through staging+conv1 for no reason (loads don't sink across
//      barriers).  First use is conv2's first MFMA: epilogue + barrier
//      hide the L2 latency.  Conv1-phase pressure drops by 72.
//  (2) e1a[3] array replaced by algebra: with x = cib^swz and cib in
//      {0,8} (no bit 4), (16+cib)^swz == x^16 EXACTLY, so
//      a1addr = e0a + 16 - ((cc&4)<<3).  XOR stays inside the 5-bit
//      sub-index (NOT R14's full-address bug).  -3 regs, +2 VALU/tap.
// Conv2 live set ~111 < 128 budget.  LDS 36,352 x 4 = 145 KB <= 160 KB.
// !! Pass/fail signal: WRITE_SIZE must be back to ~100,352 KB (no
//    scratch).  If still >105 MB: (256,4) closes PERMANENTLY, revert to
//    R16 (256,3) and pivot to fc1.
// !! e0a stays additive (R14).  LDS fills > 256 elems: strided (R8).
// h1s layout: addr(col,ci) = col*32 + (ci ^ ((col&6)<<2)).
// ---------------------------------------------------------------------------
__global__ __launch_bounds__(256, 4)
void conv_fused(const float* __restrict__ x, const float* __restrict__ b1,
                const bf16* __restrict__ w2r, const bf16* __restrict__ w1f,
                const float* __restrict__ b2, bf16* __restrict__ pooled)
{
    __shared__ __attribute__((aligned(16))) bf16  h1s[16 * 1032];   // 33024 B
    __shared__ __attribute__((aligned(16))) float mneg[98 * 4];     //  1568 B
    __shared__ __attribute__((aligned(16))) bf16  xs[640];          //  1280 B

    const int t    = threadIdx.x;
    const int lane = t & 63;
    const int wv   = t >> 6;
    const int img  = blockIdx.x >> 1;
    const int hb   = blockIdx.x & 1;        // image half
    const int nt   = wv & 1;                // conv2 cout half
    const int wp   = wv >> 1;               // conv2 Mt parity
    const int ml31 = lane & 31;
    const int lg   = lane >> 5;

    const float* xi = x + img * 784;

    const bf16x8 w1frag = *(const bf16x8*)&w1f[lane * 8];
    const float  bias2  = b2[nt * 32 + ml31];
    // conv1 bias, per-reg (cout = 4*lg + 8*run + j); dead after conv1
    f32x4 bq[4];
    #pragma unroll
    for (int run = 0; run < 4; run++)
        bq[run] = *(const f32x4*)&b1[4 * lg + 8 * run];

    // stage x tile (bf16): xs[j*32+c] = x[hb*14-2+j][c-1], rows 0..19 (pad)
    for (int e = t; e < 640; e += 256) {
        int j  = e >> 5;
        int c  = e & 31;
        int xr = hb * 14 - 2 + j;
        int xc = c - 1;
        float v = 0.f;
        if (xr >= 0 && xr < 28 && xc >= 0 && xc < 28) v = xi[xr * 28 + xc];
        xs[e] = (bf16)v;
    }
    __syncthreads();

    const u16* xu = (const u16*)xs;

    // mneg: 392 entries > 256 threads -> strided loop (R8 lesson)
    for (int e = t; e < 392; e += 256) {
        int s   = e >> 2, q = e & 3;
        int spi = s / 14, spj = s - spi * 14;
        u16 cv = xu[(2 * spi + (q >> 1) + 2) * 32 + 2 * spj + (q & 1) + 1];
        mneg[e] = ((cv & 0x7fff) != 0) ? 0.f : -1e30f;
    }

    // ---- conv1 via MFMA 32x32x16, im2col fused, operand-swapped (R16).
    // B-operand (af): lane = position col = ml31; lg picks K-half (taps).
    #pragma unroll 1
    for (int Mt = wv; Mt < 16; Mt += 4) {
        const int bb = Mt * 32 + ml31 - 1;      // window base in xu
        u16x8 tv;
        if (lg == 0) {
            tv[0] = xu[bb];      tv[1] = xu[bb + 1];  tv[2] = xu[bb + 2];
            tv[3] = xu[bb + 32]; tv[4] = xu[bb + 33]; tv[5] = xu[bb + 34];
            tv[6] = xu[bb + 64]; tv[7] = xu[bb + 65];
        } else {
            #pragma unroll
            for (int j = 0; j < 8; j++) tv[j] = 0;
            tv[0] = xu[bb + 66];                // tap 8
        }
        bf16x8 af = *(bf16x8*)&tv;

        f32x16 acc;
        #pragma unroll
        for (int run = 0; run < 4; run++)
            #pragma unroll
            for (int j = 0; j < 4; j++) acc[run * 4 + j] = bq[run][j];
        acc = __builtin_amdgcn_mfma_f32_32x32x16_bf16(w1frag, af, acc, 0, 0, 0);

        // mask: uniform per lane (one position)
        u16 ctr = xu[(Mt + 1) * 32 + ml31];
        const bool ok = (ml31 >= 1) && (ml31 <= 28) && ((ctr & 0x7fff) != 0);
        const int wbase = Mt * 1032 + ml31 * 32;
        const int swz   = (ml31 & 6) << 2;
        #pragma unroll
        for (int run = 0; run < 4; run++) {
            bf16x4 w4;
            #pragma unroll
            for (int j = 0; j < 4; j++) {
                float s = acc[run * 4 + j];
                w4[j] = (bf16)(ok ? fmaxf(s, 0.f) : 0.f);   // select: NaN-safe
            }
            const int ci0 = 4 * lg + 8 * run;
            *(bf16x4*)&h1s[wbase + (ci0 ^ swz)] = w4;
        }
    }

    // conv2 B-fragments: loaded HERE (not at kernel top) so the 72 regs are
    // not live through staging/conv1.  First use after the barrier below.
    bf16x8 breg[18];
    {
        const bf16x8* wp2 = (const bf16x8*)w2r;
        #pragma unroll
        for (int s = 0; s < 18; s++)
            breg[s] = wp2[(2 * s + nt) * 64 + lane];
    }

    __syncthreads();    // h1s + mneg ready

    // ---- conv2 Mt loop (13 tiles of 32 M-rows, 98 pooled sites)
    const int cib = lg * 8;

    int q  = ml31 & 3;
    int pj = wp * 8 + (ml31 >> 2);
    int pi = 0;
    if (pj >= 14) { pj -= 14; pi = 1; }

    bf16* pout = pooled + (long)img * 12544 + hb * 98 * 64 + nt * 32 + ml31;

    #pragma unroll 1
    for (int Mt = wp; Mt < 13; Mt += 2) {
        int row = 2 * pi + (q >> 1);
        if (row > 13) row = 13;             // keep reads (row+2) in bounds
        int colb = 2 * pj + (q & 1);
        int rowb = row * 1032;

        int e0a[3];
        #pragma unroll
        for (int dc = 0; dc < 3; dc++) {
            int cc   = colb + dc;
            int swz  = (cc & 6) << 2;
            e0a[dc] = rowb + cc * 32 + (cib ^ swz);
        }

        f32x16 acc;
        #pragma unroll
        for (int e = 0; e < 16; e++) acc[e] = bias2;   // bias in C-init

        #pragma unroll
        for (int dr = 0; dr < 3; dr++) {
            #pragma unroll
            for (int dc = 0; dc < 3; dc++) {
                const int tap = dr * 3 + dc;
                const int a0addr = e0a[dc] + dr * 1032;
                // (16+cib)^swz == (cib^swz)^16 (cib has no bit4) ->
                // +16 when swz bit4 clear, -16 when set; swz bit4 = cc&4.
                const int a1addr = a0addr + 16 - (((colb + dc) & 4) << 3);
                bf16x8 a0 = *(const bf16x8*)&h1s[a0addr];
                bf16x8 a1 = *(const bf16x8*)&h1s[a1addr];
                acc = __builtin_amdgcn_mfma_f32_32x32x16_bf16(a0, breg[2 * tap],     acc, 0, 0, 0);
                acc = __builtin_amdgcn_mfma_f32_32x32x16_bf16(a1, breg[2 * tap + 1], acc, 0, 0, 0);
            }
        }

        int slg = 8 * Mt + lg;
        #pragma unroll
        for (int gg = 0; gg < 4; gg++) {
            if (slg < 98) {
                f32x4 mn = *(const f32x4*)&mneg[slg * 4];
                float v0 = acc[gg * 4 + 0] + mn[0];
                float v1 = acc[gg * 4 + 1] + mn[1];
                float v2 = acc[gg * 4 + 2] + mn[2];
                float v3 = acc[gg * 4 + 3] + mn[3];
                float pm = fmaxf(fmaxf(v0, v1), fmaxf(v2, v3));
                pout[slg * 64] = (bf16)fmaxf(pm, 0.f);
            }
            slg += 2;
        }

        pj += 2; if (pj >= 14) { pj -= 14; pi += 1; }
        pi += 1;
    }
}

// ---------------------------------------------------------------------------
// fc1: bf16 MFMA split-K GEMM, BK=64, REGISTER-staged double buffer.
// R13: global_load_lds's prefetch is drained by the s_waitcnt vmcnt(0) the
// compiler emits before every s_barrier (m97 structural stall) -> each of 28
// iterations paid full HBM/L3 latency. Register staging moves the vmcnt wait
// AFTER the MFMAs: load next tile into 20 VGPRs during compute, then regs ->
// LDS (fast lgkm) before the barrier. Data layout identical to R12.
// ks=7 slices of 1792 k. grid (128,7) = 896 blocks (all co-resident at 4/CU).
// ---------------------------------------------------------------------------
__global__ __launch_bounds__(256, 4)
void fc1(const bf16* __restrict__ pooled, const bf16* __restrict__ wl1t,
         float* __restrict__ part)
{
    __shared__ __attribute__((aligned(16))) bf16 As[2][32 * 64];
    __shared__ __attribute__((aligned(16))) bf16 Bs[2][128 * 64];

    const int t    = threadIdx.x;
    const int lane = t & 63;
    const int wv   = t >> 6;
    const int ml   = lane & 15;
    const int kg   = lane >> 4;
    const int wm   = wv & 1;
    const int wn   = wv >> 1;
    const int m0   = blockIdx.x * 32;
    const int ks   = blockIdx.y;
    const int k0   = ks * 1792;

    // A: 256 chunks of 16B, 1/thread; chunk t -> As element t*8.
    // src: sub=(t>>7), i=t&127, r=i>>2, jq=(i&3)^((r>>1)&3)
    const bf16* asrc;
    {
        int sub = t >> 7, i = t & 127;
        int r  = i >> 2;
        int jq = (i & 3) ^ ((r >> 1) & 3);
        asrc = pooled + (long)(m0 + r) * 12544 + k0 + sub * 32 + jq * 8;
    }
    // B: 1024 chunks, 4/thread; chunk c=u*256+t -> Bs element c*8.
    const bf16* bsrc[4];
    #pragma unroll
    for (int u = 0; u < 4; u++) {
        int c  = u * 256 + t;
        int sub = c >> 9, i = c & 511;
        int r  = i >> 2;
        int jq = (i & 3) ^ ((r >> 1) & 3);
        bsrc[u] = wl1t + (long)r * 12544 + k0 + sub * 32 + jq * 8;
    }

    const int am = wm * 16 + ml;
    int aoff[2], boff[4];
    #pragma unroll
    for (int s = 0; s < 2; s++)
        aoff[s] = s * 1024 + ((am * 32 + kg * 8) ^ ((am & 6) << 2));
    #pragma unroll
    for (int j = 0; j < 4; j++) {
        int n = wn * 64 + j * 16 + ml;
        boff[j] = (n * 32 + kg * 8) ^ ((n & 6) << 2);
    }

    f32x4 acc[4];
    {
        f32x4 z = {0.f, 0.f, 0.f, 0.f};
        #pragma unroll
        for (int j = 0; j < 4; j++) acc[j] = z;
    }

    // prologue: tile 0 -> regs -> LDS[0]
    u32x4 ra = *(const u32x4*)asrc;
    u32x4 rb[4];
    #pragma unroll
    for (int u = 0; u < 4; u++) rb[u] = *(const u32x4*)bsrc[u];
    *(u32x4*)&As[0][t * 8] = ra;
    #pragma unroll
    for (int u = 0; u < 4; u++) *(u32x4*)&Bs[0][(u * 256 + t) * 8] = rb[u];

    for (int kt = 0; kt < 28; kt++) {
        __syncthreads();                    // buf[cur] visible; buf[nxt] free
        const int cur = kt & 1;
        if (kt < 27) {                      // prefetch kt+1 into registers
            const int kb = (kt + 1) * 64;
            ra = *(const u32x4*)(asrc + kb);
            #pragma unroll
            for (int u = 0; u < 4; u++) rb[u] = *(const u32x4*)(bsrc[u] + kb);
        }
        #pragma unroll
        for (int s = 0; s < 2; s++) {       // compute on cur (hides load latency)
            bf16x8 af = *(const bf16x8*)&As[cur][aoff[s]];
            #pragma unroll
            for (int j = 0; j < 4; j++) {
                bf16x8 bf = *(const bf16x8*)&Bs[cur][s * 4096 + boff[j]];
                acc[j] = __builtin_amdgcn_mfma_f32_16x16x32_bf16(af, bf, acc[j], 0, 0, 0);
            }
        }
        if (kt < 27) {                      // regs -> LDS[nxt] (vmcnt wait here)
            *(u32x4*)&As[cur ^ 1][t * 8] = ra;
            #pragma unroll
            for (int u = 0; u < 4; u++)
                *(u32x4*)&Bs[cur ^ 1][(u * 256 + t) * 8] = rb[u];
        }
    }

    float* pp = part + ((long)ks * 4096 + m0 + wm * 16) * 128 + wn * 64;
    #pragma unroll
    for (int j = 0; j < 4; j++)
        #pragma unroll
        for (int r = 0; r < 4; r++)
            pp[(kg * 4 + r) * 128 + j * 16 + ml] = acc[j][r];
}

// ---------------------------------------------------------------------------
// fc2_lsm: one wave per image; 7-way split-K reduce + FC2 + log_softmax.
// ---------------------------------------------------------------------------
__global__ __launch_bounds__(256)
void fc2_lsm(const float* __restrict__ part, const float* __restrict__ bl1,
             const float* __restrict__ Wl2, const float* __restrict__ bl2,
             float* __restrict__ out)
{
    const int wv   = threadIdx.x >> 6;
    const int lane = threadIdx.x & 63;
    const int img  = blockIdx.x * 4 + wv;
    const float* pb = part + (long)img * 128;

    float ac[10];
    #pragma unroll
    for (int c = 0; c < 10; c++) ac[c] = 0.f;

    #pragma unroll
    for (int u = 0; u < 2; u++) {
        int n = lane + 64 * u;
        float s = bl1[n];
        #pragma unroll
        for (int k = 0; k < 7; k++) s += pb[(long)k * 4096 * 128 + n];
        float h = s > 0.f ? s : 0.f;
        #pragma unroll
        for (int c = 0; c < 10; c++) ac[c] += h * Wl2[n * 10 + c];
    }
    #pragma unroll
    for (int o = 32; o > 0; o >>= 1)
        #pragma unroll
        for (int c = 0; c < 10; c++) ac[c] += __shfl_down(ac[c], o, 64);

    if (lane == 0) {
        float lg[10], mx = -1e30f;
        #pragma unroll
        for (int c = 0; c < 10; c++) {
            lg[c] = ac[c] + bl2[c];
            mx = lg[c] > mx ? lg[c] : mx;
        }
        float se = 0.f;
        #pragma unroll
        for (int c = 0; c < 10; c++) se += __expf(lg[c] - mx);
        float ls = __logf(se);
        #pragma unroll
        for (int c = 0; c < 10; c++) out[img * 10 + c] = lg[c] - mx - ls;
    }
}

// ---------------------------------------------------------------------------
extern "C" void kernel_launch(void* const* d_in, const int* in_sizes, int n_in,
                              void* d_out, int out_size, void* d_ws, size_t ws_size,
                              hipStream_t stream) {
    const float* x   = (const float*)d_in[0];
    const float* W1  = (const float*)d_in[1];
    const float* b1  = (const float*)d_in[2];
    const float* W2  = (const float*)d_in[3];
    const float* b2  = (const float*)d_in[4];
    const float* Wl1 = (const float*)d_in[5];
    const float* bl1 = (const float*)d_in[6];
    const float* Wl2 = (const float*)d_in[7];
    const float* bl2 = (const float*)d_in[8];
    float* out = (float*)d_out;

    char* ws = (char*)d_ws;
    bf16*  w2r    = (bf16*)ws;                                   // 36,864 B
    bf16*  w1f    = (bf16*)(ws + 40960);                         //  1,024 B
    bf16*  wl1t   = (bf16*)(ws + 65536);                         // 3,211,264 B
    bf16*  pooled = (bf16*)(ws + 65536 + 4194304);               // 102,760,448 B
    float* part   = (float*)(ws + 65536 + 4194304 + 102760448);  // 14,680,064 B

    prep_all  <<<466,            256, 0, stream>>>(W2, w2r, W1, w1f, Wl1, wl1t);
    conv_fused<<<8192,           256, 0, stream>>>(x, b1, w2r, w1f, b2, pooled);
    fc1       <<<dim3(128, 7),   256, 0, stream>>>(pooled, wl1t, part);
    fc2_lsm   <<<1024,           256, 0, stream>>>(part, bl1, Wl2, bl2, out);
}

// Round 9
// 251.955 us; speedup vs baseline: 1.0918x; 1.0918x over previous
//
#include <hip/hip_runtime.h>
#include <math.h>

typedef __bf16 bf16;
typedef __bf16 bf16x4 __attribute__((ext_vector_type(4)));
typedef __bf16 bf16x8 __attribute__((ext_vector_type(8)));
typedef unsigned short u16;
typedef unsigned short u16x4 __attribute__((ext_vector_type(4)));
typedef unsigned short u16x8 __attribute__((ext_vector_type(8)));
typedef float f32x4 __attribute__((ext_vector_type(4)));
typedef float f32x16 __attribute__((ext_vector_type(16)));
typedef unsigned int u32x4 __attribute__((ext_vector_type(4)));

// ---------------------------------------------------------------------------
// prep_all: merged weight-prep (one launch instead of two).
// blocks [0,392): Wl1 f32 [12544][128] -> bf16 [128][12544], K permuted
//   k' = site*64+cout <-> Wl1 row k = cout*196+site.  s=b>>1, cg=b&1.
// blocks [392,466): W2 -> conv2 B-frag buffer w2r; W1 -> conv1 B-frag w1f.
// ---------------------------------------------------------------------------
__global__ void prep_all(const float* __restrict__ W2, bf16* __restrict__ w2r,
                         const float* __restrict__ W1, bf16* __restrict__ w1f,
                         const float* __restrict__ Wl1, bf16* __restrict__ wl1t) {
    __shared__ float tile[32 * 129];
    const int b = blockIdx.x;
    const int t = threadIdx.x;
    if (b < 392) {
        const int s  = b >> 1;
        const int cg = b & 1;
        for (int e = t; e < 4096; e += 256) {
            int cl = e >> 7, n = e & 127;
            tile[cl * 129 + n] = Wl1[((long)(cg * 32 + cl) * 196 + s) * 128 + n];
        }
        __syncthreads();
        for (int e = t; e < 4096; e += 256) {
            int n = e >> 5, cl = e & 31;
            wl1t[(long)n * 12544 + s * 64 + cg * 32 + cl] = (bf16)tile[cl * 129 + n];
        }
    } else {
        int e = (b - 392) * 256 + t;
        if (e < 18432) {
            int j  = e & 7;
            int l  = (e >> 3) & 63;
            int f  = e >> 9;
            int s  = f >> 1;
            int nt = f & 1;
            int tap  = s >> 1;
            int ci   = (s & 1) * 16 + (l >> 5) * 8 + j;
            int cout = nt * 32 + (l & 31);
            w2r[e] = (bf16)W2[cout * 288 + ci * 9 + tap];
        } else {
            int e2 = e - 18432;
            if (e2 < 512) {
                int j = e2 & 7;
                int l = e2 >> 3;
                int k = (l >> 5) * 8 + j;       // tap index (K)
                int n = l & 31;                 // cout
                w1f[e2] = (k < 9) ? (bf16)W1[n * 9 + k] : (bf16)0.f;
            }
        }
    }
}

// ---------------------------------------------------------------------------
// conv_fused R20 (2nd resubmit — R7/R8 were broker infra failures; kernel
// has never executed).  If a THIRD infra failure occurs, next round submits
// R16-known-good to split flaky-broker from source-triggered failure.
// R16 structure at (256,3) + DUAL-ACCUMULATOR conv2.
// History: R17 proved the kernel LATENCY-bound (fewer LDS ops at lower
// occupancy regressed); R18/R19 proved (256,4) cannot fit — allocator
// spills (WRITE_SIZE 120->173 MB). (256,4) is CLOSED permanently.
// At fixed 3 blocks/CU the lever is the per-wave critical path: R16's 18
// conv2 MFMAs form ONE serial dependency chain through acc (C-in = prev
// C-out; ~20-30 cyc latency each, ~8 cyc issue; 3 waves/SIMD can't hide
// it).  Split: accE (even taps, a0) + accO (odd taps, a1) -> two chains
// of 9, two independent MFMA streams per wave.  +16 regs (fits the ~170
// budget; R16 measured VGPR 80 with slack), +16 VALU adds folded into
// the pooling epilogue (accE+accO+mneg).
// !! (256,4) FORBIDDEN: spills regardless of load placement (R18, R19).
// !! e0a/e1a must stay additive (R14: rowb only 8-aligned; full-address
//    XOR corrupts bit 4).
// !! LDS fills > 256 elems: strided loops (R8).
// h1s layout: addr(col,ci) = col*32 + (ci ^ ((col&6)<<2)).
// ---------------------------------------------------------------------------
__global__ __launch_bounds__(256, 3)
void conv_fused(const float* __restrict__ x, const float* __restrict__ b1,
                const bf16* __restrict__ w2r, const bf16* __restrict__ w1f,
                const float* __restrict__ b2, bf16* __restrict__ pooled)
{
    __shared__ __attribute__((aligned(16))) bf16  h1s[16 * 1032];   // 33024 B
    __shared__ __attribute__((aligned(16))) float mneg[98 * 4];     //  1568 B
    __shared__ __attribute__((aligned(16))) bf16  xs[640];          //  1280 B

    const int t    = threadIdx.x;
    const int lane = t & 63;
    const int wv   = t >> 6;
    const int img  = blockIdx.x >> 1;
    const int hb   = blockIdx.x & 1;        // image half
    const int nt   = wv & 1;                // conv2 cout half
    const int wp   = wv >> 1;               // conv2 Mt parity
    const int ml31 = lane & 31;
    const int lg   = lane >> 5;

    const float* xi = x + img * 784;

    // global loads early (L2-resident; latency hides behind staging)
    bf16x8 breg[18];
    {
        const bf16x8* wp2 = (const bf16x8*)w2r;
        #pragma unroll
        for (int s = 0; s < 18; s++)
            breg[s] = wp2[(2 * s + nt) * 64 + lane];
    }
    const bf16x8 w1frag = *(const bf16x8*)&w1f[lane * 8];
    const float  bias2  = b2[nt * 32 + ml31];
    // conv1 bias, per-reg (cout = 4*lg + 8*run + j)
    f32x4 bq[4];
    #pragma unroll
    for (int run = 0; run < 4; run++)
        bq[run] = *(const f32x4*)&b1[4 * lg + 8 * run];

    // stage x tile (bf16): xs[j*32+c] = x[hb*14-2+j][c-1], rows 0..19 (pad)
    for (int e = t; e < 640; e += 256) {
        int j  = e >> 5;
        int c  = e & 31;
        int xr = hb * 14 - 2 + j;
        int xc = c - 1;
        float v = 0.f;
        if (xr >= 0 && xr < 28 && xc >= 0 && xc < 28) v = xi[xr * 28 + xc];
        xs[e] = (bf16)v;
    }
    __syncthreads();

    const u16* xu = (const u16*)xs;

    // mneg: 392 entries > 256 threads -> strided loop (R8 lesson)
    for (int e = t; e < 392; e += 256) {
        int s   = e >> 2, q = e & 3;
        int spi = s / 14, spj = s - spi * 14;
        u16 cv = xu[(2 * spi + (q >> 1) + 2) * 32 + 2 * spj + (q & 1) + 1];
        mneg[e] = ((cv & 0x7fff) != 0) ? 0.f : -1e30f;
    }

    // ---- conv1 via MFMA 32x32x16, im2col fused, operand-swapped (R16).
    // B-operand (af): lane = position col = ml31; lg picks K-half (taps).
    #pragma unroll 1
    for (int Mt = wv; Mt < 16; Mt += 4) {
        const int bb = Mt * 32 + ml31 - 1;      // window base in xu
        u16x8 tv;
        if (lg == 0) {
            tv[0] = xu[bb];      tv[1] = xu[bb + 1];  tv[2] = xu[bb + 2];
            tv[3] = xu[bb + 32]; tv[4] = xu[bb + 33]; tv[5] = xu[bb + 34];
            tv[6] = xu[bb + 64]; tv[7] = xu[bb + 65];
        } else {
            #pragma unroll
            for (int j = 0; j < 8; j++) tv[j] = 0;
            tv[0] = xu[bb + 66];                // tap 8
        }
        bf16x8 af = *(bf16x8*)&tv;

        f32x16 acc;
        #pragma unroll
        for (int run = 0; run < 4; run++)
            #pragma unroll
            for (int j = 0; j < 4; j++) acc[run * 4 + j] = bq[run][j];
        acc = __builtin_amdgcn_mfma_f32_32x32x16_bf16(w1frag, af, acc, 0, 0, 0);

        // mask: uniform per lane (one position)
        u16 ctr = xu[(Mt + 1) * 32 + ml31];
        const bool ok = (ml31 >= 1) && (ml31 <= 28) && ((ctr & 0x7fff) != 0);
        const int wbase = Mt * 1032 + ml31 * 32;
        const int swz   = (ml31 & 6) << 2;
        #pragma unroll
        for (int run = 0; run < 4; run++) {
            bf16x4 w4;
            #pragma unroll
            for (int j = 0; j < 4; j++) {
                float s = acc[run * 4 + j];
                w4[j] = (bf16)(ok ? fmaxf(s, 0.f) : 0.f);   // select: NaN-safe
            }
            const int ci0 = 4 * lg + 8 * run;
            *(bf16x4*)&h1s[wbase + (ci0 ^ swz)] = w4;
        }
    }
    __syncthreads();    // h1s + mneg ready

    // ---- conv2 Mt loop (13 tiles of 32 M-rows, 98 pooled sites)
    const int cib = lg * 8;

    int q  = ml31 & 3;
    int pj = wp * 8 + (ml31 >> 2);
    int pi = 0;
    if (pj >= 14) { pj -= 14; pi = 1; }

    bf16* pout = pooled + (long)img * 12544 + hb * 98 * 64 + nt * 32 + ml31;

    #pragma unroll 1
    for (int Mt = wp; Mt < 13; Mt += 2) {
        int row = 2 * pi + (q >> 1);
        if (row > 13) row = 13;             // keep reads (row+2) in bounds
        int colb = 2 * pj + (q & 1);
        int rowb = row * 1032;

        int e0a[3], e1a[3];
        #pragma unroll
        for (int dc = 0; dc < 3; dc++) {
            int cc   = colb + dc;
            int swz  = (cc & 6) << 2;
            int base = rowb + cc * 32;
            e0a[dc] = base + (cib ^ swz);
            e1a[dc] = base + ((16 + cib) ^ swz);
        }

        // Dual accumulators: two independent MFMA dependency chains of 9
        // (was one chain of 18 -> latency-bound at 3 waves/SIMD).
        f32x16 accE, accO;
        #pragma unroll
        for (int e = 0; e < 16; e++) { accE[e] = bias2; accO[e] = 0.f; }

        #pragma unroll
        for (int dr = 0; dr < 3; dr++) {
            #pragma unroll
            for (int dc = 0; dc < 3; dc++) {
                const int tap = dr * 3 + dc;
                bf16x8 a0 = *(const bf16x8*)&h1s[e0a[dc] + dr * 1032];
                bf16x8 a1 = *(const bf16x8*)&h1s[e1a[dc] + dr * 1032];
                accE = __builtin_amdgcn_mfma_f32_32x32x16_bf16(a0, breg[2 * tap],     accE, 0, 0, 0);
                accO = __builtin_amdgcn_mfma_f32_32x32x16_bf16(a1, breg[2 * tap + 1], accO, 0, 0, 0);
            }
        }

        int slg = 8 * Mt + lg;
        #pragma unroll
        for (int gg = 0; gg < 4; gg++) {
            if (slg < 98) {
                f32x4 mn = *(const f32x4*)&mneg[slg * 4];
                float v0 = accE[gg * 4 + 0] + accO[gg * 4 + 0] + mn[0];
                float v1 = accE[gg * 4 + 1] + accO[gg * 4 + 1] + mn[1];
                float v2 = accE[gg * 4 + 2] + accO[gg * 4 + 2] + mn[2];
                float v3 = accE[gg * 4 + 3] + accO[gg * 4 + 3] + mn[3];
                float pm = fmaxf(fmaxf(v0, v1), fmaxf(v2, v3));
                pout[slg * 64] = (bf16)fmaxf(pm, 0.f);
            }
            slg += 2;
        }

        pj += 2; if (pj >= 14) { pj -= 14; pi += 1; }
        pi += 1;
    }
}

// ---------------------------------------------------------------------------
// fc1: bf16 MFMA split-K GEMM, BK=64, REGISTER-staged double buffer.
// R13: global_load_lds's prefetch is drained by the s_waitcnt vmcnt(0) the
// compiler emits before every s_barrier (m97 structural stall) -> each of 28
// iterations paid full HBM/L3 latency. Register staging moves the vmcnt wait
// AFTER the MFMAs: load next tile into 20 VGPRs during compute, then regs ->
// LDS (fast lgkm) before the barrier. Data layout identical to R12.
// ks=7 slices of 1792 k. grid (128,7) = 896 blocks (all co-resident at 4/CU).
// ---------------------------------------------------------------------------
__global__ __launch_bounds__(256, 4)
void fc1(const bf16* __restrict__ pooled, const bf16* __restrict__ wl1t,
         float* __restrict__ part)
{
    __shared__ __attribute__((aligned(16))) bf16 As[2][32 * 64];
    __shared__ __attribute__((aligned(16))) bf16 Bs[2][128 * 64];

    const int t    = threadIdx.x;
    const int lane = t & 63;
    const int wv   = t >> 6;
    const int ml   = lane & 15;
    const int kg   = lane >> 4;
    const int wm   = wv & 1;
    const int wn   = wv >> 1;
    const int m0   = blockIdx.x * 32;
    const int ks   = blockIdx.y;
    const int k0   = ks * 1792;

    // A: 256 chunks of 16B, 1/thread; chunk t -> As element t*8.
    // src: sub=(t>>7), i=t&127, r=i>>2, jq=(i&3)^((r>>1)&3)
    const bf16* asrc;
    {
        int sub = t >> 7, i = t & 127;
        int r  = i >> 2;
        int jq = (i & 3) ^ ((r >> 1) & 3);
        asrc = pooled + (long)(m0 + r) * 12544 + k0 + sub * 32 + jq * 8;
    }
    // B: 1024 chunks, 4/thread; chunk c=u*256+t -> Bs element c*8.
    const bf16* bsrc[4];
    #pragma unroll
    for (int u = 0; u < 4; u++) {
        int c  = u * 256 + t;
        int sub = c >> 9, i = c & 511;
        int r  = i >> 2;
        int jq = (i & 3) ^ ((r >> 1) & 3);
        bsrc[u] = wl1t + (long)r * 12544 + k0 + sub * 32 + jq * 8;
    }

    const int am = wm * 16 + ml;
    int aoff[2], boff[4];
    #pragma unroll
    for (int s = 0; s < 2; s++)
        aoff[s] = s * 1024 + ((am * 32 + kg * 8) ^ ((am & 6) << 2));
    #pragma unroll
    for (int j = 0; j < 4; j++) {
        int n = wn * 64 + j * 16 + ml;
        boff[j] = (n * 32 + kg * 8) ^ ((n & 6) << 2);
    }

    f32x4 acc[4];
    {
        f32x4 z = {0.f, 0.f, 0.f, 0.f};
        #pragma unroll
        for (int j = 0; j < 4; j++) acc[j] = z;
    }

    // prologue: tile 0 -> regs -> LDS[0]
    u32x4 ra = *(const u32x4*)asrc;
    u32x4 rb[4];
    #pragma unroll
    for (int u = 0; u < 4; u++) rb[u] = *(const u32x4*)bsrc[u];
    *(u32x4*)&As[0][t * 8] = ra;
    #pragma unroll
    for (int u = 0; u < 4; u++) *(u32x4*)&Bs[0][(u * 256 + t) * 8] = rb[u];

    for (int kt = 0; kt < 28; kt++) {
        __syncthreads();                    // buf[cur] visible; buf[nxt] free
        const int cur = kt & 1;
        if (kt < 27) {                      // prefetch kt+1 into registers
            const int kb = (kt + 1) * 64;
            ra = *(const u32x4*)(asrc + kb);
            #pragma unroll
            for (int u = 0; u < 4; u++) rb[u] = *(const u32x4*)(bsrc[u] + kb);
        }
        #pragma unroll
        for (int s = 0; s < 2; s++) {       // compute on cur (hides load latency)
            bf16x8 af = *(const bf16x8*)&As[cur][aoff[s]];
            #pragma unroll
            for (int j = 0; j < 4; j++) {
                bf16x8 bf = *(const bf16x8*)&Bs[cur][s * 4096 + boff[j]];
                acc[j] = __builtin_amdgcn_mfma_f32_16x16x32_bf16(af, bf, acc[j], 0, 0, 0);
            }
        }
        if (kt < 27) {                      // regs -> LDS[nxt] (vmcnt wait here)
            *(u32x4*)&As[cur ^ 1][t * 8] = ra;
            #pragma unroll
            for (int u = 0; u < 4; u++)
                *(u32x4*)&Bs[cur ^ 1][(u * 256 + t) * 8] = rb[u];
        }
    }

    float* pp = part + ((long)ks * 4096 + m0 + wm * 16) * 128 + wn * 64;
    #pragma unroll
    for (int j = 0; j < 4; j++)
        #pragma unroll
        for (int r = 0; r < 4; r++)
            pp[(kg * 4 + r) * 128 + j * 16 + ml] = acc[j][r];
}

// ---------------------------------------------------------------------------
// fc2_lsm: one wave per image; 7-way split-K reduce + FC2 + log_softmax.
// ---------------------------------------------------------------------------
__global__ __launch_bounds__(256)
void fc2_lsm(const float* __restrict__ part, const float* __restrict__ bl1,
             const float* __restrict__ Wl2, const float* __restrict__ bl2,
             float* __restrict__ out)
{
    const int wv   = threadIdx.x >> 6;
    const int lane = threadIdx.x & 63;
    const int img  = blockIdx.x * 4 + wv;
    const float* pb = part + (long)img * 128;

    float ac[10];
    #pragma unroll
    for (int c = 0; c < 10; c++) ac[c] = 0.f;

    #pragma unroll
    for (int u = 0; u < 2; u++) {
        int n = lane + 64 * u;
        float s = bl1[n];
        #pragma unroll
        for (int k = 0; k < 7; k++) s += pb[(long)k * 4096 * 128 + n];
        float h = s > 0.f ? s : 0.f;
        #pragma unroll
        for (int c = 0; c < 10; c++) ac[c] += h * Wl2[n * 10 + c];
    }
    #pragma unroll
    for (int o = 32; o > 0; o >>= 1)
        #pragma unroll
        for (int c = 0; c < 10; c++) ac[c] += __shfl_down(ac[c], o, 64);

    if (lane == 0) {
        float lg[10], mx = -1e30f;
        #pragma unroll
        for (int c = 0; c < 10; c++) {
            lg[c] = ac[c] + bl2[c];
            mx = lg[c] > mx ? lg[c] : mx;
        }
        float se = 0.f;
        #pragma unroll
        for (int c = 0; c < 10; c++) se += __expf(lg[c] - mx);
        float ls = __logf(se);
        #pragma unroll
        for (int c = 0; c < 10; c++) out[img * 10 + c] = lg[c] - mx - ls;
    }
}

// ---------------------------------------------------------------------------
extern "C" void kernel_launch(void* const* d_in, const int* in_sizes, int n_in,
                              void* d_out, int out_size, void* d_ws, size_t ws_size,
                              hipStream_t stream) {
    const float* x   = (const float*)d_in[0];
    const float* W1  = (const float*)d_in[1];
    const float* b1  = (const float*)d_in[2];
    const float* W2  = (const float*)d_in[3];
    const float* b2  = (const float*)d_in[4];
    const float* Wl1 = (const float*)d_in[5];
    const float* bl1 = (const float*)d_in[6];
    const float* Wl2 = (const float*)d_in[7];
    const float* bl2 = (const float*)d_in[8];
    float* out = (float*)d_out;

    char* ws = (char*)d_ws;
    bf16*  w2r    = (bf16*)ws;                                   // 36,864 B
    bf16*  w1f    = (bf16*)(ws + 40960);                         //  1,024 B
    bf16*  wl1t   = (bf16*)(ws + 65536);                         // 3,211,264 B
    bf16*  pooled = (bf16*)(ws + 65536 + 4194304);               // 102,760,448 B
    float* part   = (float*)(ws + 65536 + 4194304 + 102760448);  // 14,680,064 B

    prep_all  <<<466,            256, 0, stream>>>(W2, w2r, W1, w1f, Wl1, wl1t);
    conv_fused<<<8192,           256, 0, stream>>>(x, b1, w2r, w1f, b2, pooled);
    fc1       <<<dim3(128, 7),   256, 0, stream>>>(pooled, wl1t, part);
    fc2_lsm   <<<1024,           256, 0, stream>>>(part, bl1, Wl2, bl2, out);
}